// Round 12
// baseline (396.365 us; speedup 1.0000x reference)
//
#include <hip/hip_runtime.h>
#include <hip/hip_bf16.h>
#include <cstdint>
#include <cstddef>

// Shapes (fixed): B=8, LB=512, LC=128, H=256, H2=512, MIN_WS=5, N_WIN=4
// Windows: ws=5,10,15,20 ; n_seg=102,101,100,99 ; total 402
// d_out: out[8*256] | s_score[8*402] | b_score[8*512]  (floats)
//
// R12: 5 launches. prep -> G1(hwyL1+UHA) -> G2(hwyL2+tscore) -> L4(EW+UHT)
// -> tail(seg + mscore + final-by-last-finisher). No spin-waits: the single
// block that increments the completion counter to 4240 computes final.

typedef unsigned short ushort8 __attribute__((ext_vector_type(8)));
typedef float f32x4 __attribute__((ext_vector_type(4)));
typedef float f32x2 __attribute__((ext_vector_type(2)));

#define SS 262144

__device__ __forceinline__ float fsigmoid(float x) { return 1.0f / (1.0f + __expf(-x)); }
__device__ __forceinline__ float ftanh(float x) {
  float e = __expf(2.0f * x);
  return 1.0f - 2.0f / (e + 1.0f);
}
__device__ __forceinline__ unsigned short f2bf(float x) {
  union { float f; unsigned u; } v; v.f = x;
  unsigned r = (v.u + 0x7FFFu + ((v.u >> 16) & 1u)) >> 16;
  return (unsigned short)r;
}
__device__ __forceinline__ f32x4 mfma_bf16(ushort8 a, ushort8 b, f32x4 c) {
  asm("v_mfma_f32_16x16x32_bf16 %0, %1, %2, %0" : "+v"(c) : "v"(a), "v"(b));
  return c;
}

// ---------------- prep: weight transpose/convert + concats + wqa ---------------
struct WArg { const float* s[15]; };
__global__ __launch_bounds__(256) void prep_k(WArg wa, unsigned short* __restrict__ WT,
    const float* __restrict__ benc, const float* __restrict__ cenc,
    const float* __restrict__ cs,
    unsigned short* __restrict__ XB0, unsigned short* __restrict__ XC0,
    const float* __restrict__ aWq, const float* __restrict__ abq,
    float* __restrict__ wqa) {
  __shared__ float tile[64][65];
  const int blk = blockIdx.x, t = threadIdx.x;
  if (blk < 960) {
    const int mat = blk >> 6, q = blk & 63;
    const int Kd = (mat == 14) ? 256 : 512;
    const int k0 = (q >> 3) << 6, n0 = (q & 7) << 6;
    if (mat == 14 && (k0 >= 256 || n0 >= 256)) return;
    const float* __restrict__ S = wa.s[mat];
    unsigned short* __restrict__ D = WT + (size_t)mat * SS;
#pragma unroll
    for (int i = 0; i < 16; ++i) {
      int id = i * 256 + t, r = id >> 6, c = id & 63;
      tile[r][c] = S[(size_t)(k0 + r) * Kd + (n0 + c)];
    }
    __syncthreads();
#pragma unroll
    for (int i = 0; i < 16; ++i) {
      int id = i * 256 + t, r = id >> 6, c = id & 63;
      D[(size_t)(n0 + r) * Kd + (k0 + c)] = f2bf(tile[c][r]);
    }
  } else if (blk < 3520) {
    const bool isB = blk < 3008;
    const float* enc = isB ? benc : cenc;
    unsigned short* out = isB ? XB0 : XC0;
    const int Lshift = isB ? 9 : 7;
    int i4 = (blk - (isB ? 960 : 3008)) * 256 + t;
    int row = i4 >> 7, c4 = (i4 & 127) << 2;
    float4 v;
    if (c4 < 256) v = *(const float4*)(enc + ((size_t)row << 8) + c4);
    else          v = *(const float4*)(cs + ((size_t)(row >> Lshift) << 8) + (c4 - 256));
    union { unsigned short u[4]; uint2 w; } o;
    o.u[0] = f2bf(v.x); o.u[1] = f2bf(v.y); o.u[2] = f2bf(v.z); o.u[3] = f2bf(v.w);
    *(uint2*)(out + ((size_t)row << 9) + c4) = o.w;
  } else {
    int b = blk - 3520, h = t;
    float acc = abq[h];
    for (int k = 0; k < 256; ++k) acc += cs[b * 256 + k] * aWq[k * 256 + h];
    wqa[b * 256 + h] = acc;
  }
}

// ---------------- merged MFMA GEMM launcher ------------------------------------
// epi: 0 plain f32 (+bias if B0), 1 highway bf16 (NB=3), 2 f32 exp(2*(x+b)),
//      3 f32 exp(2*x) transposed [b][col][row&127]
struct GJob {
  const unsigned short* A; const unsigned short* W0;
  const unsigned short* W1; const unsigned short* W2;
  const float* B0; const float* B1; const float* B2;
  void* Y; int lda, N, K, nbxs /*log2 blocks in x*/, epi, nb, blk0;
};

template <int NB>
__device__ __forceinline__ void gemm_body(const GJob& j, int bx, int by,
                                          unsigned short* sm, int t) {
  const int m0 = by * 64, n0 = bx * 64;
  const int lane = t & 63, wid = t >> 6;
  const int wr = wid >> 1, wc = wid & 1;
  const int N = j.N, K = j.K, lda = j.lda;

  const int srow = t >> 3;
  const int cg = (t & 7) ^ (srow & 7);
  const unsigned short* Ag0 = j.A + (size_t)(m0 + srow) * lda + cg * 8;
  const unsigned short* Ag1 = j.A + (size_t)(m0 + 32 + srow) * lda + cg * 8;
  const unsigned short* Wp[3] = {j.W0, j.W1, j.W2};
  const unsigned short* Bg0[NB], * Bg1[NB];
#pragma unroll
  for (int p = 0; p < NB; ++p) {
    Bg0[p] = Wp[p] + (size_t)(n0 + srow) * K + cg * 8;
    Bg1[p] = Wp[p] + (size_t)(n0 + 32 + srow) * K + cg * 8;
  }
  const int d0 = t * 8, d1 = (256 + t) * 8;

  const int fl = lane & 15, lg = lane >> 4;
  int offA[2][2], offB[2][2];
#pragma unroll
  for (int f = 0; f < 2; ++f) {
    int ra = wr * 32 + f * 16 + fl;
    int rb2 = wc * 32 + f * 16 + fl;
#pragma unroll
    for (int ks = 0; ks < 2; ++ks) {
      offA[f][ks] = ra * 64 + ((((ks << 2) + lg) ^ (ra & 7)) << 3);
      offB[f][ks] = rb2 * 64 + ((((ks << 2) + lg) ^ (rb2 & 7)) << 3);
    }
  }

  f32x4 acc[NB][2][2];
#pragma unroll
  for (int p = 0; p < NB; ++p)
#pragma unroll
    for (int i = 0; i < 2; ++i)
#pragma unroll
      for (int q = 0; q < 2; ++q) acc[p][i][q] = (f32x4){0.f, 0.f, 0.f, 0.f};

  ushort8 ra0 = *(const ushort8*)Ag0, ra1 = *(const ushort8*)Ag1;
  ushort8 rb0[NB], rb1[NB];
#pragma unroll
  for (int p = 0; p < NB; ++p) { rb0[p] = *(const ushort8*)Bg0[p]; rb1[p] = *(const ushort8*)Bg1[p]; }

  for (int k0 = 0; k0 < K; k0 += 64) {
    __syncthreads();
    *(ushort8*)&sm[d0] = ra0;
    *(ushort8*)&sm[d1] = ra1;
#pragma unroll
    for (int p = 0; p < NB; ++p) {
      unsigned short* Bs = sm + (1 + p) * 4096;
      *(ushort8*)&Bs[d0] = rb0[p];
      *(ushort8*)&Bs[d1] = rb1[p];
    }
    __syncthreads();
    if (k0 + 64 < K) {
      ra0 = *(const ushort8*)(Ag0 + k0 + 64);
      ra1 = *(const ushort8*)(Ag1 + k0 + 64);
#pragma unroll
      for (int p = 0; p < NB; ++p) {
        rb0[p] = *(const ushort8*)(Bg0[p] + k0 + 64);
        rb1[p] = *(const ushort8*)(Bg1[p] + k0 + 64);
      }
    }
#pragma unroll
    for (int ks = 0; ks < 2; ++ks) {
      ushort8 a0 = *(const ushort8*)&sm[offA[0][ks]];
      ushort8 a1 = *(const ushort8*)&sm[offA[1][ks]];
#pragma unroll
      for (int p = 0; p < NB; ++p) {
        const unsigned short* Bs = sm + (1 + p) * 4096;
        ushort8 b0 = *(const ushort8*)&Bs[offB[0][ks]];
        ushort8 b1 = *(const ushort8*)&Bs[offB[1][ks]];
        acc[p][0][0] = mfma_bf16(a0, b0, acc[p][0][0]);
        acc[p][0][1] = mfma_bf16(a0, b1, acc[p][0][1]);
        acc[p][1][0] = mfma_bf16(a1, b0, acc[p][1][0]);
        acc[p][1][1] = mfma_bf16(a1, b1, acc[p][1][1]);
      }
    }
  }
  asm volatile("s_nop 7\n\ts_nop 7" ::);   // MFMA -> VALU read hazard guard

#pragma unroll
  for (int mf = 0; mf < 2; ++mf) {
#pragma unroll
    for (int nf = 0; nf < 2; ++nf) {
      const int col = n0 + wc * 32 + nf * 16 + fl;
      const int row0 = m0 + wr * 32 + mf * 16 + lg * 4;
      if constexpr (NB == 3) {
        float bn = j.B0[col], bl = j.B1[col], bg = j.B2[col];
        unsigned short* Y = (unsigned short*)j.Y;
#pragma unroll
        for (int e = 0; e < 4; ++e) {
          float nv = acc[0][mf][nf][e] + bn;
          float lv = acc[1][mf][nf][e] + bl;
          float gv = fsigmoid(acc[2][mf][nf][e] + bg);
          Y[(size_t)(row0 + e) * N + col] = f2bf(gv * fmaxf(nv, 0.f) + (1.f - gv) * lv);
        }
      } else {
        float* Y = (float*)j.Y;
        if (j.epi == 2) {
          float bb = j.B0[col];
#pragma unroll
          for (int e = 0; e < 4; ++e)
            Y[(size_t)(row0 + e) * N + col] = __expf(2.0f * (acc[0][mf][nf][e] + bb));
        } else if (j.epi == 3) {
          f32x4 w;
#pragma unroll
          for (int e = 0; e < 4; ++e) w[e] = __expf(2.0f * acc[0][mf][nf][e]);
          *(f32x4*)(Y + (((size_t)(row0 >> 7)) << 16) + ((size_t)col << 7) + (row0 & 127)) = w;
        } else {
          float bb = j.B0 ? j.B0[col] : 0.f;
#pragma unroll
          for (int e = 0; e < 4; ++e)
            Y[(size_t)(row0 + e) * N + col] = acc[0][mf][nf][e] + bb;
        }
      }
    }
  }
}

// merged kernel: up to 3 gemm jobs + tail blocks (tmode 1=tscore)
__global__ __launch_bounds__(256) void mgemm3_k(GJob j0, GJob j1, GJob j2,
    int toff, int tmode,
    const float* __restrict__ p0, const float* __restrict__ p1,
    const float* __restrict__ p2, float* __restrict__ pout) {
  __shared__ unsigned short sm[4 * 4096];
  const int blk = blockIdx.x, t = threadIdx.x;
  if (blk >= toff) {
    const int rel = blk - toff;
    if (tmode == 1) {
      // tscore: t[pos] = sum_h tanh(wqa[b,h]+uha[pos,h])*av[h]
      const int lane = t & 63, wid = t >> 6;
      const int pos = (rel << 2) + wid;
      const int b = pos >> 9;
      const int h0 = lane << 2;
      float4 u = *(const float4*)(p0 + (size_t)pos * 256 + h0);
      float4 w = *(const float4*)(p1 + b * 256 + h0);
      float4 v = *(const float4*)(p2 + h0);
      float s = ftanh(w.x + u.x) * v.x + ftanh(w.y + u.y) * v.y +
                ftanh(w.z + u.z) * v.z + ftanh(w.w + u.w) * v.w;
#pragma unroll
      for (int off = 32; off; off >>= 1) s += __shfl_xor(s, off);
      if (lane == 0) pout[pos] = s;
    }
    return;
  }
  GJob j = j0;
  if (blk >= j1.blk0) j = j1;
  if (blk >= j2.blk0) j = j2;
  const int rel = blk - j.blk0;
  const int bx = rel & ((1 << j.nbxs) - 1), by = rel >> j.nbxs;
  if (j.nb == 3) gemm_body<3>(j, bx, by, sm, t);
  else          gemm_body<1>(j, bx, by, sm, t);
}

// ---- mscore body: per-element rcp; wave = h-quarter, 4 rows -------------------
__device__ __forceinline__ void ms_comp(const float* eb, const float* vbp, int h0,
    f32x2 u0, f32x2 u1, f32x2 u2, f32x2 u3,
    f32x2& a0, f32x2& a1, f32x2& a2, f32x2& a3) {
  f32x4 v4 = *(const f32x4*)(vbp + h0);
#pragma unroll
  for (int r = 0; r < 4; ++r) {
    f32x2& ar = (r == 0) ? a0 : (r == 1) ? a1 : (r == 2) ? a2 : a3;
    f32x4 e4 = *(const f32x4*)(eb + r * 512 + h0);
    ar.x = __builtin_fmaf(v4[0], __builtin_amdgcn_rcpf(__builtin_fmaf(e4[0], u0.x, 1.f)), ar.x);
    ar.y = __builtin_fmaf(v4[0], __builtin_amdgcn_rcpf(__builtin_fmaf(e4[0], u0.y, 1.f)), ar.y);
    ar.x = __builtin_fmaf(v4[1], __builtin_amdgcn_rcpf(__builtin_fmaf(e4[1], u1.x, 1.f)), ar.x);
    ar.y = __builtin_fmaf(v4[1], __builtin_amdgcn_rcpf(__builtin_fmaf(e4[1], u1.y, 1.f)), ar.y);
    ar.x = __builtin_fmaf(v4[2], __builtin_amdgcn_rcpf(__builtin_fmaf(e4[2], u2.x, 1.f)), ar.x);
    ar.y = __builtin_fmaf(v4[2], __builtin_amdgcn_rcpf(__builtin_fmaf(e4[2], u2.y, 1.f)), ar.y);
    ar.x = __builtin_fmaf(v4[3], __builtin_amdgcn_rcpf(__builtin_fmaf(e4[3], u3.x, 1.f)), ar.x);
    ar.y = __builtin_fmaf(v4[3], __builtin_amdgcn_rcpf(__builtin_fmaf(e4[3], u3.y, 1.f)), ar.y);
  }
}

__device__ void mscore_body(int vb, int t, float* smem,
                            const float* __restrict__ EW,
                            const float* __restrict__ UHT,
                            const float* __restrict__ mv,
                            float* __restrict__ bscore) {
  float* ews = smem;            // [4][512]
  float* vvs = smem + 2048;     // [512]
  const int lane = t & 63, w = t >> 6;   // w = h-quarter
  const int row0 = vb << 2;
  const int b = row0 >> 9;
#pragma unroll
  for (int q = 0; q < 2; ++q) {
    int f4 = q * 256 + t, r = f4 >> 7, c4 = (f4 & 127) << 2;
    *(float4*)&ews[r * 512 + c4] =
        *(const float4*)(EW + (((size_t)(row0 + r)) << 9) + c4);
  }
  if (t < 128) *(float4*)&vvs[t << 2] = *(const float4*)(mv + (t << 2));
  __syncthreads();

  const float* up = UHT + ((size_t)b << 16) + (w << 14) + (lane << 1);
  const float* eb = ews + (w << 7);
  const float* vbp = vvs + (w << 7);

  f32x2 a0 = {0.f, 0.f}, a1 = {0.f, 0.f}, a2 = {0.f, 0.f}, a3 = {0.f, 0.f};
  f32x2 uA0, uA1, uA2, uA3, uB0, uB1, uB2, uB3;
  uA0 = *(const f32x2*)(up + 0 * 128);
  uA1 = *(const f32x2*)(up + 1 * 128);
  uA2 = *(const f32x2*)(up + 2 * 128);
  uA3 = *(const f32x2*)(up + 3 * 128);
#pragma unroll
  for (int i = 0; i < 32; i += 2) {
    const int hB = (i + 1) * 4, hN = (i + 2) * 4;
    uB0 = *(const f32x2*)(up + (size_t)(hB + 0) * 128);
    uB1 = *(const f32x2*)(up + (size_t)(hB + 1) * 128);
    uB2 = *(const f32x2*)(up + (size_t)(hB + 2) * 128);
    uB3 = *(const f32x2*)(up + (size_t)(hB + 3) * 128);
    ms_comp(eb, vbp, i * 4, uA0, uA1, uA2, uA3, a0, a1, a2, a3);
    if (i + 2 < 32) {
      uA0 = *(const f32x2*)(up + (size_t)(hN + 0) * 128);
      uA1 = *(const f32x2*)(up + (size_t)(hN + 1) * 128);
      uA2 = *(const f32x2*)(up + (size_t)(hN + 2) * 128);
      uA3 = *(const f32x2*)(up + (size_t)(hN + 3) * 128);
    }
    ms_comp(eb, vbp, hB, uB0, uB1, uB2, uB3, a0, a1, a2, a3);
  }

  __syncthreads();              // e-reads done; alias ews as part
  float* part = smem;           // [hq][r][128]
  *(f32x2*)&part[((w * 4 + 0) * 128) + (lane << 1)] = a0;
  *(f32x2*)&part[((w * 4 + 1) * 128) + (lane << 1)] = a1;
  *(f32x2*)&part[((w * 4 + 2) * 128) + (lane << 1)] = a2;
  *(f32x2*)&part[((w * 4 + 3) * 128) + (lane << 1)] = a3;
  __syncthreads();

  {
    const int r = w;            // wave w reduces row w
    f32x2 s0 = *(const f32x2*)&part[((0 * 4 + r) * 128) + (lane << 1)];
    f32x2 s1 = *(const f32x2*)&part[((1 * 4 + r) * 128) + (lane << 1)];
    f32x2 s2 = *(const f32x2*)&part[((2 * 4 + r) * 128) + (lane << 1)];
    f32x2 s3 = *(const f32x2*)&part[((3 * 4 + r) * 128) + (lane << 1)];
    float sx = s0.x + s1.x + s2.x + s3.x;
    float sy = s0.y + s1.y + s2.y + s3.y;
    float m = fminf(sx, sy);
#pragma unroll
    for (int off = 32; off; off >>= 1) m = fminf(m, __shfl_xor(m, off));
    float V = 0.f;
#pragma unroll
    for (int k = 0; k < 8; ++k) V += vvs[lane + (k << 6)];
#pragma unroll
    for (int off = 32; off; off >>= 1) V += __shfl_xor(V, off);
    if (lane == 0) bscore[row0 + r] = V - 2.f * m;
  }
}

// ---- final (runs on the single last-finisher block, loops all 8 b) ------------
__device__ void final8_body(int t, float* smem,
                            const float* __restrict__ bscore,
                            const float* __restrict__ seg,
                            float* __restrict__ dout) {
  float* sc   = smem;           // [402]
  float* bsc  = smem + 402;     // [512]
  float* redm = smem + 914;     // [4]
  float* reds = smem + 918;     // [4]
  const int lane = t & 63, wid = t >> 6;
  for (int b = 0; b < 8; ++b) {
    __syncthreads();
    for (int i = t; i < 512; i += 256) bsc[i] = bscore[b * 512 + i];
    __syncthreads();
    for (int s = t; s < 402; s += 256) {
      int i, n;
      if (s < 102)      { i = 0; n = s; }
      else if (s < 203) { i = 1; n = s - 102; }
      else if (s < 303) { i = 2; n = s - 203; }
      else              { i = 3; n = s - 303; }
      const int ws = 5 * (i + 1), start = n * 5;
      float ss = 0.f;
      for (int w = 0; w < ws; ++w) ss += bsc[start + w];
      sc[s] = ss;
    }
    __syncthreads();
    float m = -3.0e38f;
    for (int s = t; s < 402; s += 256) m = fmaxf(m, sc[s]);
#pragma unroll
    for (int off = 32; off; off >>= 1) m = fmaxf(m, __shfl_xor(m, off));
    if (lane == 0) redm[wid] = m;
    __syncthreads();
    m = fmaxf(fmaxf(redm[0], redm[1]), fmaxf(redm[2], redm[3]));
    float p = 0.f;
    for (int s = t; s < 402; s += 256) p += __expf(sc[s] - m);
#pragma unroll
    for (int off = 32; off; off >>= 1) p += __shfl_xor(p, off);
    if (lane == 0) reds[wid] = p;
    __syncthreads();
    float invS = 1.f / (reds[0] + reds[1] + reds[2] + reds[3]);
    for (int s = t; s < 402; s += 256) {
      float pv = __expf(sc[s] - m) * invS;
      dout[2048 + b * 402 + s] = pv;
      sc[s] = pv;
    }
    __syncthreads();
    float acc = 0.f;
    for (int s = 0; s < 402; ++s)
      acc += sc[s] * seg[((size_t)(b * 402 + s)) * 256 + t];
    dout[b * 256 + t] = acc;
  }
}

// ---- tail: seg (3216) + mscore (1024) + final by last finisher ---------------
__global__ __launch_bounds__(256) void tail_k(
    const float* __restrict__ T, const float* __restrict__ benc,
    float* __restrict__ SEG,
    const float* __restrict__ EW, const float* __restrict__ UHT,
    const float* __restrict__ mv, float* __restrict__ bscore,
    float* __restrict__ dout, unsigned* __restrict__ cnt) {
  __shared__ __align__(16) float smem[2560];   // mscore 10KB; final reuses
  __shared__ int lastflag;
  const int blk = blockIdx.x, t = threadIdx.x;

  if (blk < 3216) {
    // seg: per-(b,s) window softmax over T, weighted b_enc sum
    const int b = blk / 402, s = blk - b * 402;
    const int h = t;
    int i, n;
    if (s < 102)      { i = 0; n = s; }
    else if (s < 203) { i = 1; n = s - 102; }
    else if (s < 303) { i = 2; n = s - 203; }
    else              { i = 3; n = s - 303; }
    const int ws = 5 * (i + 1), start = n * 5;
    const float* tb = T + b * 512 + start;
    float mx = -3.0e38f;
    for (int w = 0; w < ws; ++w) mx = fmaxf(mx, tb[w]);
    float sum = 0.f;
    for (int w = 0; w < ws; ++w) sum += __expf(tb[w] - mx);
    float inv = 1.f / sum;
    float acc = 0.f;
    for (int w = 0; w < ws; ++w)
      acc += __expf(tb[w] - mx) * benc[((size_t)(b * 512 + start + w)) * 256 + h];
    SEG[((size_t)(b * 402 + s)) * 256 + h] = acc * inv;
  } else {
    mscore_body(blk - 3216, t, smem, EW, UHT, mv, bscore);
  }

  // completion protocol: barrier drains this block's stores; t0 flushes L2 and
  // increments the device counter; the 4240th finisher computes final.
  __syncthreads();
  if (t == 0) {
    __threadfence();
    unsigned r = atomicAdd(cnt, 1u);
    lastflag = (r == 4239u);
    if (lastflag)
      (void)__hip_atomic_load(cnt, __ATOMIC_ACQUIRE, __HIP_MEMORY_SCOPE_AGENT);
  }
  __syncthreads();
  if (lastflag) final8_body(t, smem, bscore, SEG, dout);
}

extern "C" void kernel_launch(void* const* d_in, const int* in_sizes, int n_in,
                              void* d_out, int out_size, void* d_ws, size_t ws_size,
                              hipStream_t stream) {
  const float* b_enc   = (const float*)d_in[0];
  const float* c_enc   = (const float*)d_in[1];
  const float* c_state = (const float*)d_in[2];
  const float* bh_Wn = (const float*)d_in[5];
  const float* bh_bn = (const float*)d_in[6];
  const float* bh_Wl = (const float*)d_in[7];
  const float* bh_bl = (const float*)d_in[8];
  const float* bh_Wg = (const float*)d_in[9];
  const float* bh_bg = (const float*)d_in[10];
  const float* ch_Wn = (const float*)d_in[11];
  const float* ch_bn = (const float*)d_in[12];
  const float* ch_Wl = (const float*)d_in[13];
  const float* ch_bl = (const float*)d_in[14];
  const float* ch_Wg = (const float*)d_in[15];
  const float* ch_bg = (const float*)d_in[16];
  const float* m_Wq  = (const float*)d_in[17];
  const float* m_bq  = (const float*)d_in[18];
  const float* m_Wk  = (const float*)d_in[19];
  const float* m_v   = (const float*)d_in[20];
  const float* a_Wq  = (const float*)d_in[21];
  const float* a_bq  = (const float*)d_in[22];
  const float* a_Wk  = (const float*)d_in[23];
  const float* a_v   = (const float*)d_in[24];

  uint8_t* base = (uint8_t*)d_ws;
  unsigned short* WT  = (unsigned short*)(base);            // 14 x 512x512 bf16
  unsigned short* WTa = WT + 14 * SS;                       // 256x256 bf16
  unsigned short* XB0 = (unsigned short*)(base + 7471104);  // 4096x512 bf16
  unsigned short* XB1 = (unsigned short*)(base + 11665408); // 4096x512 bf16
  unsigned short* XC0 = (unsigned short*)(base + 15859712); // 1024x512 bf16
  unsigned short* XC1 = (unsigned short*)(base + 16908288); // 1024x512 bf16
  float* EW   = (float*)(base + 17956864);                  // 4096x512 f32
  float* UHT  = (float*)(base + 26345472);                  // 8x512x128 f32
  float* UHA  = (float*)(base + 28442624);                  // 4096x256 f32
  float* WQA  = (float*)(base + 32636928);
  float* T    = (float*)(base + 32645120);
  float* SEG  = (float*)(base + 32661504);                  // 8x402x256 f32
  unsigned* CNT = (unsigned*)(base + 35954688);

  float* out = (float*)d_out;
  float* BSC = out + 5264;

  const int LW = 262144;
  const int SENT = 1 << 30;

  WArg wa;
  wa.s[0] = bh_Wn; wa.s[1] = bh_Wn + LW;
  wa.s[2] = bh_Wl; wa.s[3] = bh_Wl + LW;
  wa.s[4] = bh_Wg; wa.s[5] = bh_Wg + LW;
  wa.s[6] = ch_Wn; wa.s[7] = ch_Wn + LW;
  wa.s[8] = ch_Wl; wa.s[9] = ch_Wl + LW;
  wa.s[10] = ch_Wg; wa.s[11] = ch_Wg + LW;
  wa.s[12] = m_Wq; wa.s[13] = m_Wk; wa.s[14] = a_Wk;

  hipMemsetAsync(CNT, 0, 4, stream);

  // L1: prep
  prep_k<<<3528, 256, 0, stream>>>(wa, WT, b_enc, c_enc, c_state, XB0, XC0,
                                   a_Wq, a_bq, WQA);

  // L2 (G1): hwy-b L1 (512) + hwy-c L1 (128) + UHA gemm (256)
  {
    GJob jb = {XB0, WT, WT + 2 * SS, WT + 4 * SS, bh_bn, bh_bl, bh_bg,
               XB1, 512, 512, 512, 3, 1, 3, 0};
    GJob jc = {XC0, WT + 6 * SS, WT + 8 * SS, WT + 10 * SS, ch_bn, ch_bl, ch_bg,
               XC1, 512, 512, 512, 3, 1, 3, 512};
    GJob ja = {XB0, WTa, nullptr, nullptr, nullptr, nullptr, nullptr,
               UHA, 512, 256, 256, 2, 0, 1, 640};
    mgemm3_k<<<896, 256, 0, stream>>>(jb, jc, ja, 896, 0,
                                      nullptr, nullptr, nullptr, nullptr);
  }
  // L3 (G2): hwy-b L2 (512) + hwy-c L2 (128) + tscore tail (1024)
  {
    GJob jb = {XB1, WT + SS, WT + 3 * SS, WT + 5 * SS,
               bh_bn + 512, bh_bl + 512, bh_bg + 512, XB0, 512, 512, 512, 3, 1, 3, 0};
    GJob jc = {XC1, WT + 7 * SS, WT + 9 * SS, WT + 11 * SS,
               ch_bn + 512, ch_bl + 512, ch_bg + 512, XC0, 512, 512, 512, 3, 1, 3, 512};
    GJob js = jc; js.blk0 = SENT;
    mgemm3_k<<<1664, 256, 0, stream>>>(jb, jc, js, 640, 1, UHA, WQA, a_v, T);
  }
  // L4: EW gemm (512) + UHT gemm (128)
  {
    GJob je = {XB0, WT + 12 * SS, nullptr, nullptr, m_bq, nullptr, nullptr,
               EW, 512, 512, 512, 3, 2, 1, 0};
    GJob ju = {XC0, WT + 13 * SS, nullptr, nullptr, nullptr, nullptr, nullptr,
               UHT, 512, 512, 512, 3, 3, 1, 512};
    GJob js = ju; js.blk0 = SENT;
    mgemm3_k<<<640, 256, 0, stream>>>(je, ju, js, 640, 0,
                                      nullptr, nullptr, nullptr, nullptr);
  }
  // L5: seg (3216) + mscore (1024) + final (last finisher)
  tail_k<<<4240, 256, 0, stream>>>(T, b_enc, SEG, EW, UHT, m_v, BSC, out, CNT);
}

// Round 13
// 137.560 us; speedup vs baseline: 2.8814x; 2.8814x over previous
//
#include <hip/hip_runtime.h>
#include <hip/hip_bf16.h>
#include <cstdint>
#include <cstddef>

// Shapes (fixed): B=8, LB=512, LC=128, H=256, H2=512, MIN_WS=5, N_WIN=4
// Windows: ws=5,10,15,20 ; n_seg=102,101,100,99 ; total 402
// d_out: out[8*256] | s_score[8*402] | b_score[8*512]  (floats)
//
// R13: R11 structure (6 launches, no cross-block sync — R9/R10/R12 proved
// device-scope sync on 8-XCD MI355X costs O(L2-flush) per participant).
// One change vs R11: gemm_body staging via __builtin_amdgcn_global_load_lds
// width=16 (direct-to-LDS, async), replacing reg-staging. LDS dest linear,
// global source pre-swizzled, reads swizzled — bytes land identically.

typedef unsigned short ushort8 __attribute__((ext_vector_type(8)));
typedef float f32x4 __attribute__((ext_vector_type(4)));
typedef float f32x2 __attribute__((ext_vector_type(2)));

#define SS 262144

__device__ __forceinline__ float fsigmoid(float x) { return 1.0f / (1.0f + __expf(-x)); }
__device__ __forceinline__ float ftanh(float x) {
  float e = __expf(2.0f * x);
  return 1.0f - 2.0f / (e + 1.0f);
}
__device__ __forceinline__ unsigned short f2bf(float x) {
  union { float f; unsigned u; } v; v.f = x;
  unsigned r = (v.u + 0x7FFFu + ((v.u >> 16) & 1u)) >> 16;
  return (unsigned short)r;
}
__device__ __forceinline__ f32x4 mfma_bf16(ushort8 a, ushort8 b, f32x4 c) {
  asm("v_mfma_f32_16x16x32_bf16 %0, %1, %2, %0" : "+v"(c) : "v"(a), "v"(b));
  return c;
}
__device__ __forceinline__ void gload16(const unsigned short* g, unsigned short* l) {
  __builtin_amdgcn_global_load_lds(
      (const __attribute__((address_space(1))) uint32_t*)g,
      (__attribute__((address_space(3))) uint32_t*)l, 16, 0, 0);
}

// ---------------- prep: weight transpose/convert + concats + wqa ---------------
struct WArg { const float* s[15]; };
__global__ __launch_bounds__(256) void prep_k(WArg wa, unsigned short* __restrict__ WT,
    const float* __restrict__ benc, const float* __restrict__ cenc,
    const float* __restrict__ cs,
    unsigned short* __restrict__ XB0, unsigned short* __restrict__ XC0,
    const float* __restrict__ aWq, const float* __restrict__ abq,
    float* __restrict__ wqa) {
  __shared__ float tile[64][65];
  const int blk = blockIdx.x, t = threadIdx.x;
  if (blk < 960) {
    const int mat = blk >> 6, q = blk & 63;
    const int Kd = (mat == 14) ? 256 : 512;
    const int k0 = (q >> 3) << 6, n0 = (q & 7) << 6;
    if (mat == 14 && (k0 >= 256 || n0 >= 256)) return;
    const float* __restrict__ S = wa.s[mat];
    unsigned short* __restrict__ D = WT + (size_t)mat * SS;
#pragma unroll
    for (int i = 0; i < 16; ++i) {
      int id = i * 256 + t, r = id >> 6, c = id & 63;
      tile[r][c] = S[(size_t)(k0 + r) * Kd + (n0 + c)];
    }
    __syncthreads();
#pragma unroll
    for (int i = 0; i < 16; ++i) {
      int id = i * 256 + t, r = id >> 6, c = id & 63;
      D[(size_t)(n0 + r) * Kd + (k0 + c)] = f2bf(tile[c][r]);
    }
  } else if (blk < 3520) {
    const bool isB = blk < 3008;
    const float* enc = isB ? benc : cenc;
    unsigned short* out = isB ? XB0 : XC0;
    const int Lshift = isB ? 9 : 7;
    int i4 = (blk - (isB ? 960 : 3008)) * 256 + t;
    int row = i4 >> 7, c4 = (i4 & 127) << 2;
    float4 v;
    if (c4 < 256) v = *(const float4*)(enc + ((size_t)row << 8) + c4);
    else          v = *(const float4*)(cs + ((size_t)(row >> Lshift) << 8) + (c4 - 256));
    union { unsigned short u[4]; uint2 w; } o;
    o.u[0] = f2bf(v.x); o.u[1] = f2bf(v.y); o.u[2] = f2bf(v.z); o.u[3] = f2bf(v.w);
    *(uint2*)(out + ((size_t)row << 9) + c4) = o.w;
  } else {
    int b = blk - 3520, h = t;
    float acc = abq[h];
    for (int k = 0; k < 256; ++k) acc += cs[b * 256 + k] * aWq[k * 256 + h];
    wqa[b * 256 + h] = acc;
  }
}

// ---------------- merged MFMA GEMM launcher ------------------------------------
// epi: 0 plain f32 (+bias if B0), 1 highway bf16 (NB=3), 2 f32 exp(2*(x+b)),
//      3 f32 exp(2*x) transposed [b][col][row&127]
struct GJob {
  const unsigned short* A; const unsigned short* W0;
  const unsigned short* W1; const unsigned short* W2;
  const float* B0; const float* B1; const float* B2;
  void* Y; int lda, N, K, nbxs /*log2 blocks in x*/, epi, nb, blk0;
};

template <int NB>
__device__ __forceinline__ void gemm_body(const GJob& j, int bx, int by,
                                          unsigned short* sm, int t) {
  const int m0 = by * 64, n0 = bx * 64;
  const int lane = t & 63, wid = t >> 6;
  const int wr = wid >> 1, wc = wid & 1;
  const int N = j.N, K = j.K, lda = j.lda;

  // staging: thread t owns 16B chunks d0=(t) and d1=(t+256) of each 8KB tile.
  // LDS dest LINEAR (global_load_lds: wave-uniform base + lane*16B);
  // global source chunk pre-swizzled so swizzled READS see linear k.
  const int srow = t >> 3;
  const int cg = (t & 7) ^ (srow & 7);
  const unsigned short* Ag0 = j.A + (size_t)(m0 + srow) * lda + cg * 8;
  const unsigned short* Ag1 = j.A + (size_t)(m0 + 32 + srow) * lda + cg * 8;
  const unsigned short* Wp[3] = {j.W0, j.W1, j.W2};
  const unsigned short* Bg0[NB], * Bg1[NB];
#pragma unroll
  for (int p = 0; p < NB; ++p) {
    Bg0[p] = Wp[p] + (size_t)(n0 + srow) * K + cg * 8;
    Bg1[p] = Wp[p] + (size_t)(n0 + 32 + srow) * K + cg * 8;
  }
  const int d0 = t * 8, d1 = (256 + t) * 8;

  const int fl = lane & 15, lg = lane >> 4;
  int offA[2][2], offB[2][2];
#pragma unroll
  for (int f = 0; f < 2; ++f) {
    int ra = wr * 32 + f * 16 + fl;
    int rb2 = wc * 32 + f * 16 + fl;
#pragma unroll
    for (int ks = 0; ks < 2; ++ks) {
      offA[f][ks] = ra * 64 + ((((ks << 2) + lg) ^ (ra & 7)) << 3);
      offB[f][ks] = rb2 * 64 + ((((ks << 2) + lg) ^ (rb2 & 7)) << 3);
    }
  }

  f32x4 acc[NB][2][2];
#pragma unroll
  for (int p = 0; p < NB; ++p)
#pragma unroll
    for (int i = 0; i < 2; ++i)
#pragma unroll
      for (int q = 0; q < 2; ++q) acc[p][i][q] = (f32x4){0.f, 0.f, 0.f, 0.f};

  for (int k0 = 0; k0 < K; k0 += 64) {
    __syncthreads();                 // WAR: previous tile's reads complete
    gload16(Ag0 + k0, sm + d0);
    gload16(Ag1 + k0, sm + d1);
#pragma unroll
    for (int p = 0; p < NB; ++p) {
      unsigned short* Bs = sm + (1 + p) * 4096;
      gload16(Bg0[p] + k0, Bs + d0);
      gload16(Bg1[p] + k0, Bs + d1);
    }
    __syncthreads();                 // compiler drains vmcnt before s_barrier
#pragma unroll
    for (int ks = 0; ks < 2; ++ks) {
      ushort8 a0 = *(const ushort8*)&sm[offA[0][ks]];
      ushort8 a1 = *(const ushort8*)&sm[offA[1][ks]];
#pragma unroll
      for (int p = 0; p < NB; ++p) {
        const unsigned short* Bs = sm + (1 + p) * 4096;
        ushort8 b0 = *(const ushort8*)&Bs[offB[0][ks]];
        ushort8 b1 = *(const ushort8*)&Bs[offB[1][ks]];
        acc[p][0][0] = mfma_bf16(a0, b0, acc[p][0][0]);
        acc[p][0][1] = mfma_bf16(a0, b1, acc[p][0][1]);
        acc[p][1][0] = mfma_bf16(a1, b0, acc[p][1][0]);
        acc[p][1][1] = mfma_bf16(a1, b1, acc[p][1][1]);
      }
    }
  }
  asm volatile("s_nop 7\n\ts_nop 7" ::);   // MFMA -> VALU read hazard guard

#pragma unroll
  for (int mf = 0; mf < 2; ++mf) {
#pragma unroll
    for (int nf = 0; nf < 2; ++nf) {
      const int col = n0 + wc * 32 + nf * 16 + fl;
      const int row0 = m0 + wr * 32 + mf * 16 + lg * 4;
      if constexpr (NB == 3) {
        float bn = j.B0[col], bl = j.B1[col], bg = j.B2[col];
        unsigned short* Y = (unsigned short*)j.Y;
#pragma unroll
        for (int e = 0; e < 4; ++e) {
          float nv = acc[0][mf][nf][e] + bn;
          float lv = acc[1][mf][nf][e] + bl;
          float gv = fsigmoid(acc[2][mf][nf][e] + bg);
          Y[(size_t)(row0 + e) * N + col] = f2bf(gv * fmaxf(nv, 0.f) + (1.f - gv) * lv);
        }
      } else {
        float* Y = (float*)j.Y;
        if (j.epi == 2) {
          float bb = j.B0[col];
#pragma unroll
          for (int e = 0; e < 4; ++e)
            Y[(size_t)(row0 + e) * N + col] = __expf(2.0f * (acc[0][mf][nf][e] + bb));
        } else if (j.epi == 3) {
          f32x4 w;
#pragma unroll
          for (int e = 0; e < 4; ++e) w[e] = __expf(2.0f * acc[0][mf][nf][e]);
          *(f32x4*)(Y + (((size_t)(row0 >> 7)) << 16) + ((size_t)col << 7) + (row0 & 127)) = w;
        } else {
          float bb = j.B0 ? j.B0[col] : 0.f;
#pragma unroll
          for (int e = 0; e < 4; ++e)
            Y[(size_t)(row0 + e) * N + col] = acc[0][mf][nf][e] + bb;
        }
      }
    }
  }
}

// merged kernel: up to 3 gemm jobs + tail blocks (tmode 1=tscore, 2=seg)
__global__ __launch_bounds__(256) void mgemm3_k(GJob j0, GJob j1, GJob j2,
    int toff, int tmode,
    const float* __restrict__ p0,   // tscore: UHA ; seg: T
    const float* __restrict__ p1,   // tscore: WQA ; seg: benc
    const float* __restrict__ p2,   // tscore: a_v ; seg: (unused)
    float* __restrict__ pout) {     // tscore: T   ; seg: SEG
  __shared__ unsigned short sm[4 * 4096];
  const int blk = blockIdx.x, t = threadIdx.x;
  if (blk >= toff) {
    const int rel = blk - toff;
    if (tmode == 1) {
      // tscore: t[pos] = sum_h tanh(wqa[b,h]+uha[pos,h])*av[h]
      const int lane = t & 63, wid = t >> 6;
      const int pos = (rel << 2) + wid;
      const int b = pos >> 9;
      const int h0 = lane << 2;
      float4 u = *(const float4*)(p0 + (size_t)pos * 256 + h0);
      float4 w = *(const float4*)(p1 + b * 256 + h0);
      float4 v = *(const float4*)(p2 + h0);
      float s = ftanh(w.x + u.x) * v.x + ftanh(w.y + u.y) * v.y +
                ftanh(w.z + u.z) * v.z + ftanh(w.w + u.w) * v.w;
#pragma unroll
      for (int off = 32; off; off >>= 1) s += __shfl_xor(s, off);
      if (lane == 0) pout[pos] = s;
    } else {
      // seg: per-(b,s) window softmax over T, weighted b_enc sum
      const int b = rel / 402, s = rel - b * 402;
      const int h = t;
      int i, n;
      if (s < 102)      { i = 0; n = s; }
      else if (s < 203) { i = 1; n = s - 102; }
      else if (s < 303) { i = 2; n = s - 203; }
      else              { i = 3; n = s - 303; }
      const int ws = 5 * (i + 1), start = n * 5;
      const float* tb = p0 + b * 512 + start;
      float mx = -3.0e38f;
      for (int w = 0; w < ws; ++w) mx = fmaxf(mx, tb[w]);
      float sum = 0.f;
      for (int w = 0; w < ws; ++w) sum += __expf(tb[w] - mx);
      float inv = 1.f / sum;
      float acc = 0.f;
      for (int w = 0; w < ws; ++w)
        acc += __expf(tb[w] - mx) * p1[((size_t)(b * 512 + start + w)) * 256 + h];
      pout[((size_t)(b * 402 + s)) * 256 + h] = acc * inv;
    }
    return;
  }
  GJob j = j0;
  if (blk >= j1.blk0) j = j1;
  if (blk >= j2.blk0) j = j2;
  const int rel = blk - j.blk0;
  const int bx = rel & ((1 << j.nbxs) - 1), by = rel >> j.nbxs;
  if (j.nb == 3) gemm_body<3>(j, bx, by, sm, t);
  else          gemm_body<1>(j, bx, by, sm, t);
}

// ---- mscore: per-element rcp; wave = h-quarter, 4 rows/block, 1024 blocks -----
// tanh(a+b) = 1 - 2/(1+EwEu); b_score = V - 2*min_j sum_h v/(1+EwEu)
__device__ __forceinline__ void ms_comp(const float* eb, const float* vbp, int h0,
    f32x2 u0, f32x2 u1, f32x2 u2, f32x2 u3,
    f32x2& a0, f32x2& a1, f32x2& a2, f32x2& a3) {
  f32x4 v4 = *(const f32x4*)(vbp + h0);
#pragma unroll
  for (int r = 0; r < 4; ++r) {
    f32x2& ar = (r == 0) ? a0 : (r == 1) ? a1 : (r == 2) ? a2 : a3;
    f32x4 e4 = *(const f32x4*)(eb + r * 512 + h0);
    ar.x = __builtin_fmaf(v4[0], __builtin_amdgcn_rcpf(__builtin_fmaf(e4[0], u0.x, 1.f)), ar.x);
    ar.y = __builtin_fmaf(v4[0], __builtin_amdgcn_rcpf(__builtin_fmaf(e4[0], u0.y, 1.f)), ar.y);
    ar.x = __builtin_fmaf(v4[1], __builtin_amdgcn_rcpf(__builtin_fmaf(e4[1], u1.x, 1.f)), ar.x);
    ar.y = __builtin_fmaf(v4[1], __builtin_amdgcn_rcpf(__builtin_fmaf(e4[1], u1.y, 1.f)), ar.y);
    ar.x = __builtin_fmaf(v4[2], __builtin_amdgcn_rcpf(__builtin_fmaf(e4[2], u2.x, 1.f)), ar.x);
    ar.y = __builtin_fmaf(v4[2], __builtin_amdgcn_rcpf(__builtin_fmaf(e4[2], u2.y, 1.f)), ar.y);
    ar.x = __builtin_fmaf(v4[3], __builtin_amdgcn_rcpf(__builtin_fmaf(e4[3], u3.x, 1.f)), ar.x);
    ar.y = __builtin_fmaf(v4[3], __builtin_amdgcn_rcpf(__builtin_fmaf(e4[3], u3.y, 1.f)), ar.y);
  }
}

__global__ __launch_bounds__(256) void mscore_k(const float* __restrict__ EW,
                                                const float* __restrict__ UHT,
                                                const float* __restrict__ mv,
                                                float* __restrict__ bscore) {
  __shared__ __align__(16) float smem[4 * 512 + 512];  // ews[4][512] | vvs[512]
  float* ews = smem;
  float* vvs = smem + 2048;
  const int t = threadIdx.x, lane = t & 63, w = t >> 6;  // w = h-quarter
  const int vb = blockIdx.x;             // 1024 blocks, 4 rows each
  const int row0 = vb << 2;
  const int b = row0 >> 9;
#pragma unroll
  for (int q = 0; q < 2; ++q) {
    int f4 = q * 256 + t, r = f4 >> 7, c4 = (f4 & 127) << 2;
    *(float4*)&ews[r * 512 + c4] =
        *(const float4*)(EW + (((size_t)(row0 + r)) << 9) + c4);
  }
  if (t < 128) *(float4*)&vvs[t << 2] = *(const float4*)(mv + (t << 2));
  __syncthreads();

  const float* up = UHT + ((size_t)b << 16) + (w << 14) + (lane << 1);
  const float* eb = ews + (w << 7);
  const float* vbp = vvs + (w << 7);

  f32x2 a0 = {0.f, 0.f}, a1 = {0.f, 0.f}, a2 = {0.f, 0.f}, a3 = {0.f, 0.f};
  f32x2 uA0, uA1, uA2, uA3, uB0, uB1, uB2, uB3;
  uA0 = *(const f32x2*)(up + 0 * 128);
  uA1 = *(const f32x2*)(up + 1 * 128);
  uA2 = *(const f32x2*)(up + 2 * 128);
  uA3 = *(const f32x2*)(up + 3 * 128);
#pragma unroll
  for (int i = 0; i < 32; i += 2) {
    const int hB = (i + 1) * 4, hN = (i + 2) * 4;
    uB0 = *(const f32x2*)(up + (size_t)(hB + 0) * 128);
    uB1 = *(const f32x2*)(up + (size_t)(hB + 1) * 128);
    uB2 = *(const f32x2*)(up + (size_t)(hB + 2) * 128);
    uB3 = *(const f32x2*)(up + (size_t)(hB + 3) * 128);
    ms_comp(eb, vbp, i * 4, uA0, uA1, uA2, uA3, a0, a1, a2, a3);
    if (i + 2 < 32) {
      uA0 = *(const f32x2*)(up + (size_t)(hN + 0) * 128);
      uA1 = *(const f32x2*)(up + (size_t)(hN + 1) * 128);
      uA2 = *(const f32x2*)(up + (size_t)(hN + 2) * 128);
      uA3 = *(const f32x2*)(up + (size_t)(hN + 3) * 128);
    }
    ms_comp(eb, vbp, hB, uB0, uB1, uB2, uB3, a0, a1, a2, a3);
  }

  __syncthreads();                       // e-reads done; alias ews as part
  float* part = smem;                    // [hq][r][128]
  *(f32x2*)&part[((w * 4 + 0) * 128) + (lane << 1)] = a0;
  *(f32x2*)&part[((w * 4 + 1) * 128) + (lane << 1)] = a1;
  *(f32x2*)&part[((w * 4 + 2) * 128) + (lane << 1)] = a2;
  *(f32x2*)&part[((w * 4 + 3) * 128) + (lane << 1)] = a3;
  __syncthreads();

  {
    const int r = w;                     // wave w reduces row w
    f32x2 s0 = *(const f32x2*)&part[((0 * 4 + r) * 128) + (lane << 1)];
    f32x2 s1 = *(const f32x2*)&part[((1 * 4 + r) * 128) + (lane << 1)];
    f32x2 s2 = *(const f32x2*)&part[((2 * 4 + r) * 128) + (lane << 1)];
    f32x2 s3 = *(const f32x2*)&part[((3 * 4 + r) * 128) + (lane << 1)];
    float sx = s0.x + s1.x + s2.x + s3.x;
    float sy = s0.y + s1.y + s2.y + s3.y;
    float m = fminf(sx, sy);
#pragma unroll
    for (int off = 32; off; off >>= 1) m = fminf(m, __shfl_xor(m, off));
    float V = 0.f;
#pragma unroll
    for (int k = 0; k < 8; ++k) V += vvs[lane + (k << 6)];
#pragma unroll
    for (int off = 32; off; off >>= 1) V += __shfl_xor(V, off);
    if (lane == 0) bscore[row0 + r] = V - 2.f * m;
  }
}

// ---- final: SCO from b_score, softmax, out = s_score @ segments ---------------
__global__ __launch_bounds__(256) void final_k(const float* __restrict__ bscore,
                                               const float* __restrict__ seg,
                                               float* __restrict__ dout) {
  const int b = blockIdx.x, t = threadIdx.x, lane = t & 63, wid = t >> 6;
  __shared__ float sc[402];
  __shared__ float bsc[512];
  __shared__ float redm[4], reds[4];
  for (int i = t; i < 512; i += 256) bsc[i] = bscore[b * 512 + i];
  __syncthreads();
  for (int s = t; s < 402; s += 256) {
    int i, n;
    if (s < 102)      { i = 0; n = s; }
    else if (s < 203) { i = 1; n = s - 102; }
    else if (s < 303) { i = 2; n = s - 203; }
    else              { i = 3; n = s - 303; }
    const int ws = 5 * (i + 1), start = n * 5;
    float ss = 0.f;
    for (int w = 0; w < ws; ++w) ss += bsc[start + w];
    sc[s] = ss;
  }
  __syncthreads();
  float m = -3.0e38f;
  for (int s = t; s < 402; s += 256) m = fmaxf(m, sc[s]);
#pragma unroll
  for (int off = 32; off; off >>= 1) m = fmaxf(m, __shfl_xor(m, off));
  if (lane == 0) redm[wid] = m;
  __syncthreads();
  m = fmaxf(fmaxf(redm[0], redm[1]), fmaxf(redm[2], redm[3]));
  float p = 0.f;
  for (int s = t; s < 402; s += 256) p += __expf(sc[s] - m);
#pragma unroll
  for (int off = 32; off; off >>= 1) p += __shfl_xor(p, off);
  if (lane == 0) reds[wid] = p;
  __syncthreads();
  float invS = 1.f / (reds[0] + reds[1] + reds[2] + reds[3]);
  for (int s = t; s < 402; s += 256) {
    float pv = __expf(sc[s] - m) * invS;
    dout[2048 + b * 402 + s] = pv;
    sc[s] = pv;
  }
  __syncthreads();
  float acc = 0.f;
  for (int s = 0; s < 402; ++s)
    acc += sc[s] * seg[((size_t)(b * 402 + s)) * 256 + t];
  dout[b * 256 + t] = acc;
}

extern "C" void kernel_launch(void* const* d_in, const int* in_sizes, int n_in,
                              void* d_out, int out_size, void* d_ws, size_t ws_size,
                              hipStream_t stream) {
  const float* b_enc   = (const float*)d_in[0];
  const float* c_enc   = (const float*)d_in[1];
  const float* c_state = (const float*)d_in[2];
  const float* bh_Wn = (const float*)d_in[5];
  const float* bh_bn = (const float*)d_in[6];
  const float* bh_Wl = (const float*)d_in[7];
  const float* bh_bl = (const float*)d_in[8];
  const float* bh_Wg = (const float*)d_in[9];
  const float* bh_bg = (const float*)d_in[10];
  const float* ch_Wn = (const float*)d_in[11];
  const float* ch_bn = (const float*)d_in[12];
  const float* ch_Wl = (const float*)d_in[13];
  const float* ch_bl = (const float*)d_in[14];
  const float* ch_Wg = (const float*)d_in[15];
  const float* ch_bg = (const float*)d_in[16];
  const float* m_Wq  = (const float*)d_in[17];
  const float* m_bq  = (const float*)d_in[18];
  const float* m_Wk  = (const float*)d_in[19];
  const float* m_v   = (const float*)d_in[20];
  const float* a_Wq  = (const float*)d_in[21];
  const float* a_bq  = (const float*)d_in[22];
  const float* a_Wk  = (const float*)d_in[23];
  const float* a_v   = (const float*)d_in[24];

  uint8_t* base = (uint8_t*)d_ws;
  unsigned short* WT  = (unsigned short*)(base);            // 14 x 512x512 bf16
  unsigned short* WTa = WT + 14 * SS;                       // 256x256 bf16
  unsigned short* XB0 = (unsigned short*)(base + 7471104);  // 4096x512 bf16
  unsigned short* XB1 = (unsigned short*)(base + 11665408); // 4096x512 bf16
  unsigned short* XC0 = (unsigned short*)(base + 15859712); // 1024x512 bf16
  unsigned short* XC1 = (unsigned short*)(base + 16908288); // 1024x512 bf16
  float* EW   = (float*)(base + 17956864);                  // 4096x512 f32
  float* UHT  = (float*)(base + 26345472);                  // 8x512x128 f32
  float* UHA  = (float*)(base + 28442624);                  // 4096x256 f32
  float* WQA  = (float*)(base + 32636928);
  float* T    = (float*)(base + 32645120);
  float* SEG  = (float*)(base + 32661504);                  // 8x402x256 f32

  float* out = (float*)d_out;
  float* BSC = out + 5264;

  const int LW = 262144;
  const int SENT = 1 << 30;

  WArg wa;
  wa.s[0] = bh_Wn; wa.s[1] = bh_Wn + LW;
  wa.s[2] = bh_Wl; wa.s[3] = bh_Wl + LW;
  wa.s[4] = bh_Wg; wa.s[5] = bh_Wg + LW;
  wa.s[6] = ch_Wn; wa.s[7] = ch_Wn + LW;
  wa.s[8] = ch_Wl; wa.s[9] = ch_Wl + LW;
  wa.s[10] = ch_Wg; wa.s[11] = ch_Wg + LW;
  wa.s[12] = m_Wq; wa.s[13] = m_Wk; wa.s[14] = a_Wk;

  // L1: prep
  prep_k<<<3528, 256, 0, stream>>>(wa, WT, b_enc, c_enc, c_state, XB0, XC0,
                                   a_Wq, a_bq, WQA);

  // L2 (G1): hwy-b L1 (512) + hwy-c L1 (128) + UHA gemm (256)
  {
    GJob jb = {XB0, WT, WT + 2 * SS, WT + 4 * SS, bh_bn, bh_bl, bh_bg,
               XB1, 512, 512, 512, 3, 1, 3, 0};
    GJob jc = {XC0, WT + 6 * SS, WT + 8 * SS, WT + 10 * SS, ch_bn, ch_bl, ch_bg,
               XC1, 512, 512, 512, 3, 1, 3, 512};
    GJob ja = {XB0, WTa, nullptr, nullptr, nullptr, nullptr, nullptr,
               UHA, 512, 256, 256, 2, 0, 1, 640};
    mgemm3_k<<<896, 256, 0, stream>>>(jb, jc, ja, 896, 0,
                                      nullptr, nullptr, nullptr, nullptr);
  }
  // L3 (G2): hwy-b L2 (512) + hwy-c L2 (128) + tscore tail (1024)
  {
    GJob jb = {XB1, WT + SS, WT + 3 * SS, WT + 5 * SS,
               bh_bn + 512, bh_bl + 512, bh_bg + 512, XB0, 512, 512, 512, 3, 1, 3, 0};
    GJob jc = {XC1, WT + 7 * SS, WT + 9 * SS, WT + 11 * SS,
               ch_bn + 512, ch_bl + 512, ch_bg + 512, XC0, 512, 512, 512, 3, 1, 3, 512};
    GJob js = jc; js.blk0 = SENT;
    mgemm3_k<<<1664, 256, 0, stream>>>(jb, jc, js, 640, 1, UHA, WQA, a_v, T);
  }
  // L4 (G3): EW gemm (512) + UHT gemm (128) + seg tail (3216)
  {
    GJob je = {XB0, WT + 12 * SS, nullptr, nullptr, m_bq, nullptr, nullptr,
               EW, 512, 512, 512, 3, 2, 1, 0};
    GJob ju = {XC0, WT + 13 * SS, nullptr, nullptr, nullptr, nullptr, nullptr,
               UHT, 512, 512, 512, 3, 3, 1, 512};
    GJob js = ju; js.blk0 = SENT;
    mgemm3_k<<<3856, 256, 0, stream>>>(je, ju, js, 640, 2, T, b_enc, nullptr, SEG);
  }
  // L5: mscore
  mscore_k<<<1024, 256, 0, stream>>>(EW, UHT, m_v, BSC);
  // L6: final (computes SCO from b_score internally)
  final_k<<<8, 256, 0, stream>>>(BSC, SEG, out);
}